// Round 11
// baseline (241.098 us; speedup 1.0000x reference)
//
#include <hip/hip_runtime.h>

#define DH 30
#define SLOPE 0.01f

typedef float v2 __attribute__((ext_vector_type(2)));

// ws layout (floats): W1p[9][32] @0, W2p[30][32] @288, W3p[30][32] @1248,
// b1p[32] @2208, b2p[32] @2240, b3p[32] @2272, W4p[32] @2304, b4 @2336.
// Pad columns (30,31) are zero.
#define W1_OFF 0
#define W2_OFF 288
#define W3_OFF 1248
#define B1_OFF 2208
#define B2_OFF 2240
#define B3_OFF 2272
#define W4_OFF 2304
#define B4_OFF 2336

__global__ __launch_bounds__(256) void pack_w(
    const float* __restrict__ W1, const float* __restrict__ b1,
    const float* __restrict__ W2, const float* __restrict__ b2,
    const float* __restrict__ W3, const float* __restrict__ b3,
    const float* __restrict__ W4, const float* __restrict__ b4,
    float* __restrict__ ws)
{
    for (int idx = threadIdx.x; idx < 2368; idx += 256) {
        float v = 0.f;
        if (idx < 288)        { int t = idx,        r = t >> 5, c = t & 31; v = (c < DH) ? W1[r * DH + c] : 0.f; }
        else if (idx < 1248)  { int t = idx - 288,  r = t >> 5, c = t & 31; v = (c < DH) ? W2[r * DH + c] : 0.f; }
        else if (idx < 2208)  { int t = idx - 1248, r = t >> 5, c = t & 31; v = (c < DH) ? W3[r * DH + c] : 0.f; }
        else if (idx < 2240)  { int c = idx - 2208; v = (c < DH) ? b1[c] : 0.f; }
        else if (idx < 2272)  { int c = idx - 2240; v = (c < DH) ? b2[c] : 0.f; }
        else if (idx < 2304)  { int c = idx - 2272; v = (c < DH) ? b3[c] : 0.f; }
        else if (idx < 2336)  { int c = idx - 2304; v = (c < DH) ? W4[c] : 0.f; }
        else if (idx == 2336) { v = b4[0]; }
        ws[idx] = v;
    }
}

// Weights via scalar pipe from PACKED ws (32-float rows, 128B-aligned ->
// 2x s_load_dwordx16 per row, ~3x fewer SMEM ops/wait points than the
// unaligned 30-float rows). R9 proved weights must stay in SGPRs; R10
// proved forcing VGPR below ~70 spills. Natural allocation (~84) is optimal.
__global__ __launch_bounds__(256) void mlp_fwdbwd(
    const float4* __restrict__ pe,
    const float*  __restrict__ q,
    const float4* __restrict__ s,
    const float* __restrict__ ws,
    float* __restrict__ dout, int n)
{
    const int i = blockIdx.x * 256 + threadIdx.x;
    if (i >= n) return;

    const float4 vpe = pe[i];
    const float4 vs  = s[i];
    const float  vq  = q[i];
    float x[9] = { vpe.x, vpe.y, vpe.z, vpe.w, vq, vs.x, vs.y, vs.z, vs.w };

    v2 acc[16];
    v2 hh[16];
    unsigned m1 = 0, m2 = 0, m3 = 0;
    const v2 slope2 = { SLOPE, SLOPE };

    // ---- layer 1: (x @ W1) then + b1 (acc from 0, k ascending, fma) ----
    #pragma unroll
    for (int jj = 0; jj < 16; ++jj) acc[jj] = (v2){0.f, 0.f};
    #pragma unroll
    for (int k = 0; k < 9; ++k) {
        const v2 xv = { x[k], x[k] };
        const v2* Wr = reinterpret_cast<const v2*>(ws + W1_OFF + k * 32);
        #pragma unroll
        for (int jj = 0; jj < 16; ++jj)
            acc[jj] = __builtin_elementwise_fma(xv, Wr[jj], acc[jj]);
    }
    {
        const v2* bv = reinterpret_cast<const v2*>(ws + B1_OFF);
        #pragma unroll
        for (int jj = 0; jj < 16; ++jj) {
            const v2 z = acc[jj] + bv[jj];
            if (z.x > 0.f) m1 |= (1u << (2*jj));
            if (z.y > 0.f) m1 |= (1u << (2*jj+1));
            // bit-identical to (z>0?z:0.01*z)
            hh[jj] = __builtin_elementwise_max(z, z * slope2);
        }
    }

    // ---- layer 2 ----
    #pragma unroll
    for (int jj = 0; jj < 16; ++jj) acc[jj] = (v2){0.f, 0.f};
    #pragma unroll
    for (int k = 0; k < DH; ++k) {
        const float hk = hh[k >> 1][k & 1];
        const v2 hv = { hk, hk };
        const v2* Wr = reinterpret_cast<const v2*>(ws + W2_OFF + k * 32);
        #pragma unroll
        for (int jj = 0; jj < 16; ++jj)
            acc[jj] = __builtin_elementwise_fma(hv, Wr[jj], acc[jj]);
    }
    {
        const v2* bv = reinterpret_cast<const v2*>(ws + B2_OFF);
        #pragma unroll
        for (int jj = 0; jj < 16; ++jj) {
            const v2 z = acc[jj] + bv[jj];
            if (z.x > 0.f) m2 |= (1u << (2*jj));
            if (z.y > 0.f) m2 |= (1u << (2*jj+1));
            hh[jj] = __builtin_elementwise_max(z, z * slope2);
        }
    }

    // ---- layer 3 ----
    #pragma unroll
    for (int jj = 0; jj < 16; ++jj) acc[jj] = (v2){0.f, 0.f};
    #pragma unroll
    for (int k = 0; k < DH; ++k) {
        const float hk = hh[k >> 1][k & 1];
        const v2 hv = { hk, hk };
        const v2* Wr = reinterpret_cast<const v2*>(ws + W3_OFF + k * 32);
        #pragma unroll
        for (int jj = 0; jj < 16; ++jj)
            acc[jj] = __builtin_elementwise_fma(hv, Wr[jj], acc[jj]);
    }
    // output dot: scalar, j ascending (bit-identical to passing R6/R8 kernels)
    const float* b3p = ws + B3_OFF;
    const float* W4p = ws + W4_OFF;
    float outv = 0.f;
    #pragma unroll
    for (int j = 0; j < DH; ++j) {
        const float z = acc[j >> 1][j & 1] + b3p[j];
        if (z > 0.f) m3 |= (1u << j);
        const float hz = (z > 0.f) ? z : SLOPE * z;
        outv = fmaf(hz, W4p[j], outv);
    }
    outv += ws[B4_OFF];

    // ---- backward (mask-driven; value-continuous, packed dots) ----
    v2 g3[16];
    {
        const v2* w4v = reinterpret_cast<const v2*>(W4p);
        #pragma unroll
        for (int jj = 0; jj < 16; ++jj) {
            const v2 w = w4v[jj];
            g3[jj].x = ((m3 >> (2*jj))   & 1u) ? w.x : SLOPE * w.x;  // pads: w=0 -> 0
            g3[jj].y = ((m3 >> (2*jj+1)) & 1u) ? w.y : SLOPE * w.y;
        }
    }
    v2 g2[16];
    g2[15] = (v2){0.f, 0.f};
    #pragma unroll
    for (int k = 0; k < DH; ++k) {
        v2 d = (v2){0.f, 0.f};
        const v2* Wr = reinterpret_cast<const v2*>(ws + W3_OFF + k * 32);
        #pragma unroll
        for (int jj = 0; jj < 16; ++jj)
            d = __builtin_elementwise_fma(g3[jj], Wr[jj], d);
        const float dot = d.x + d.y;
        g2[k >> 1][k & 1] = ((m2 >> k) & 1u) ? dot : SLOPE * dot;
    }
    v2 g1[16];
    g1[15] = (v2){0.f, 0.f};
    #pragma unroll
    for (int k = 0; k < DH; ++k) {
        v2 d = (v2){0.f, 0.f};
        const v2* Wr = reinterpret_cast<const v2*>(ws + W2_OFF + k * 32);
        #pragma unroll
        for (int jj = 0; jj < 16; ++jj)
            d = __builtin_elementwise_fma(g2[jj], Wr[jj], d);
        const float dot = d.x + d.y;
        g1[k >> 1][k & 1] = ((m1 >> k) & 1u) ? dot : SLOPE * dot;
    }
    float gx[9];
    #pragma unroll
    for (int k = 0; k < 9; ++k) {
        v2 d = (v2){0.f, 0.f};
        const v2* Wr = reinterpret_cast<const v2*>(ws + W1_OFF + k * 32);
        #pragma unroll
        for (int jj = 0; jj < 16; ++jj)
            d = __builtin_elementwise_fma(g1[jj], Wr[jj], d);
        gx[k] = d.x + d.y;
    }

    // ---- stores: [out(N) | h_s(4N) | h_q(N) | h_pe(4N)] ----
    dout[i] = outv;
    float4* hs = reinterpret_cast<float4*>(dout + (size_t)n);
    hs[i] = make_float4(gx[5], gx[6], gx[7], gx[8]);
    dout[(size_t)5 * n + i] = gx[4];
    float4* hpe = reinterpret_cast<float4*>(dout + (size_t)6 * n);
    hpe[i] = make_float4(gx[0], gx[1], gx[2], gx[3]);
}

extern "C" void kernel_launch(void* const* d_in, const int* in_sizes, int n_in,
                              void* d_out, int out_size, void* d_ws, size_t ws_size,
                              hipStream_t stream) {
    const int n = in_sizes[1];  // input_q has N elements
    float* ws = (float*)d_ws;
    hipLaunchKernelGGL(pack_w, dim3(1), dim3(256), 0, stream,
        (const float*)d_in[3], (const float*)d_in[4],
        (const float*)d_in[5], (const float*)d_in[6],
        (const float*)d_in[7], (const float*)d_in[8],
        (const float*)d_in[9], (const float*)d_in[10],
        ws);
    const int blocks = (n + 255) / 256;
    hipLaunchKernelGGL(mlp_fwdbwd, dim3(blocks), dim3(256), 0, stream,
        (const float4*)d_in[0], (const float*)d_in[1], (const float4*)d_in[2],
        (const float*)ws, (float*)d_out, n);
}

// Round 12
// 214.695 us; speedup vs baseline: 1.1230x; 1.1230x over previous
//
#include <hip/hip_runtime.h>

#define DH 30
#define SLOPE 0.01f

typedef float v2 __attribute__((ext_vector_type(2)));

// Weights via scalar pipe (wave-uniform, compile-time offsets -> s_load ->
// SGPR pair -> packed v_pk_fma_f32). R9: weights must stay in SGPRs (LDS/
// VMEM paths -> VGPR blowup + spills). R10: forcing VGPR below the ~75 live
// set spills; natural ~84 is optimal. R11: SMEM op count/alignment neutral.
// R12: 64-thread blocks (1 wave/workgroup) to let the CU scheduler fill
// SIMDs to the VGPR limit without 4-wave block granularity.
__global__ __launch_bounds__(64) void mlp_fwdbwd(
    const float4* __restrict__ pe,
    const float*  __restrict__ q,
    const float4* __restrict__ s,
    const float* __restrict__ W1, const float* __restrict__ b1,
    const float* __restrict__ W2, const float* __restrict__ b2,
    const float* __restrict__ W3, const float* __restrict__ b3,
    const float* __restrict__ W4, const float* __restrict__ b4,
    float* __restrict__ dout, int n)
{
    const int i = blockIdx.x * 64 + threadIdx.x;
    if (i >= n) return;

    const float4 vpe = pe[i];
    const float4 vs  = s[i];
    const float  vq  = q[i];
    float x[9] = { vpe.x, vpe.y, vpe.z, vpe.w, vq, vs.x, vs.y, vs.z, vs.w };

    v2 acc[15];
    v2 hh[15];
    unsigned m1 = 0, m2 = 0, m3 = 0;
    const v2 slope2 = { SLOPE, SLOPE };

    // ---- layer 1: (x @ W1) then + b1 (acc from 0, k ascending, fma) ----
    #pragma unroll
    for (int jj = 0; jj < 15; ++jj) acc[jj] = (v2){0.f, 0.f};
    #pragma unroll
    for (int k = 0; k < 9; ++k) {
        const v2 xv = { x[k], x[k] };
        const v2* Wr = reinterpret_cast<const v2*>(W1 + k * DH);
        #pragma unroll
        for (int jj = 0; jj < 15; ++jj)
            acc[jj] = __builtin_elementwise_fma(xv, Wr[jj], acc[jj]);
    }
    {
        const v2* bv = reinterpret_cast<const v2*>(b1);
        #pragma unroll
        for (int jj = 0; jj < 15; ++jj) {
            const v2 z = acc[jj] + bv[jj];
            if (z.x > 0.f) m1 |= (1u << (2*jj));
            if (z.y > 0.f) m1 |= (1u << (2*jj+1));
            // bit-identical to (z>0?z:0.01*z)
            hh[jj] = __builtin_elementwise_max(z, z * slope2);
        }
    }

    // ---- layer 2 ----
    #pragma unroll
    for (int jj = 0; jj < 15; ++jj) acc[jj] = (v2){0.f, 0.f};
    #pragma unroll
    for (int k = 0; k < DH; ++k) {
        const float hk = hh[k >> 1][k & 1];
        const v2 hv = { hk, hk };
        const v2* Wr = reinterpret_cast<const v2*>(W2 + k * DH);
        #pragma unroll
        for (int jj = 0; jj < 15; ++jj)
            acc[jj] = __builtin_elementwise_fma(hv, Wr[jj], acc[jj]);
    }
    {
        const v2* bv = reinterpret_cast<const v2*>(b2);
        #pragma unroll
        for (int jj = 0; jj < 15; ++jj) {
            const v2 z = acc[jj] + bv[jj];
            if (z.x > 0.f) m2 |= (1u << (2*jj));
            if (z.y > 0.f) m2 |= (1u << (2*jj+1));
            hh[jj] = __builtin_elementwise_max(z, z * slope2);
        }
    }

    // ---- layer 3 ----
    #pragma unroll
    for (int jj = 0; jj < 15; ++jj) acc[jj] = (v2){0.f, 0.f};
    #pragma unroll
    for (int k = 0; k < DH; ++k) {
        const float hk = hh[k >> 1][k & 1];
        const v2 hv = { hk, hk };
        const v2* Wr = reinterpret_cast<const v2*>(W3 + k * DH);
        #pragma unroll
        for (int jj = 0; jj < 15; ++jj)
            acc[jj] = __builtin_elementwise_fma(hv, Wr[jj], acc[jj]);
    }
    // output dot: scalar, j ascending (bit-identical to passing R6/R8 kernels)
    float outv = 0.f;
    #pragma unroll
    for (int j = 0; j < DH; ++j) {
        const float z = acc[j >> 1][j & 1] + b3[j];
        if (z > 0.f) m3 |= (1u << j);
        const float hz = (z > 0.f) ? z : SLOPE * z;
        outv = fmaf(hz, W4[j], outv);
    }
    outv += b4[0];

    // ---- backward (mask-driven; value-continuous, packed dots) ----
    v2 g3[15];
    {
        const v2* w4v = reinterpret_cast<const v2*>(W4);
        #pragma unroll
        for (int jj = 0; jj < 15; ++jj) {
            const v2 w = w4v[jj];
            g3[jj].x = ((m3 >> (2*jj))   & 1u) ? w.x : SLOPE * w.x;
            g3[jj].y = ((m3 >> (2*jj+1)) & 1u) ? w.y : SLOPE * w.y;
        }
    }
    v2 g2[15];
    #pragma unroll
    for (int k = 0; k < DH; ++k) {
        v2 d = (v2){0.f, 0.f};
        const v2* Wr = reinterpret_cast<const v2*>(W3 + k * DH);
        #pragma unroll
        for (int jj = 0; jj < 15; ++jj)
            d = __builtin_elementwise_fma(g3[jj], Wr[jj], d);
        const float dot = d.x + d.y;
        g2[k >> 1][k & 1] = ((m2 >> k) & 1u) ? dot : SLOPE * dot;
    }
    v2 g1[15];
    #pragma unroll
    for (int k = 0; k < DH; ++k) {
        v2 d = (v2){0.f, 0.f};
        const v2* Wr = reinterpret_cast<const v2*>(W2 + k * DH);
        #pragma unroll
        for (int jj = 0; jj < 15; ++jj)
            d = __builtin_elementwise_fma(g2[jj], Wr[jj], d);
        const float dot = d.x + d.y;
        g1[k >> 1][k & 1] = ((m1 >> k) & 1u) ? dot : SLOPE * dot;
    }
    float gx[9];
    #pragma unroll
    for (int k = 0; k < 9; ++k) {
        v2 d = (v2){0.f, 0.f};
        const v2* Wr = reinterpret_cast<const v2*>(W1 + k * DH);
        #pragma unroll
        for (int jj = 0; jj < 15; ++jj)
            d = __builtin_elementwise_fma(g1[jj], Wr[jj], d);
        gx[k] = d.x + d.y;
    }

    // ---- stores: [out(N) | h_s(4N) | h_q(N) | h_pe(4N)] ----
    dout[i] = outv;
    float4* hs = reinterpret_cast<float4*>(dout + (size_t)n);
    hs[i] = make_float4(gx[5], gx[6], gx[7], gx[8]);
    dout[(size_t)5 * n + i] = gx[4];
    float4* hpe = reinterpret_cast<float4*>(dout + (size_t)6 * n);
    hpe[i] = make_float4(gx[0], gx[1], gx[2], gx[3]);
}

extern "C" void kernel_launch(void* const* d_in, const int* in_sizes, int n_in,
                              void* d_out, int out_size, void* d_ws, size_t ws_size,
                              hipStream_t stream) {
    const int n = in_sizes[1];  // input_q has N elements
    const int blocks = (n + 63) / 64;
    hipLaunchKernelGGL(mlp_fwdbwd, dim3(blocks), dim3(64), 0, stream,
        (const float4*)d_in[0], (const float*)d_in[1], (const float4*)d_in[2],
        (const float*)d_in[3], (const float*)d_in[4],
        (const float*)d_in[5], (const float*)d_in[6],
        (const float*)d_in[7], (const float*)d_in[8],
        (const float*)d_in[9], (const float*)d_in[10],
        (float*)d_out, n);
}

// Round 13
// 151.830 us; speedup vs baseline: 1.5879x; 1.4140x over previous
//
#include <hip/hip_runtime.h>

#define DH 30
#define SLOPE 0.01f

typedef float v2 __attribute__((ext_vector_type(2)));
#define SB() __builtin_amdgcn_sched_barrier(0)

// LDS layout (floats): W1[9][32]@0, W2[30][32]@288, W3[30][32]@1248,
// b1[32]@2208, b2[32]@2240, b3[32]@2272, W4[32]@2304, b4@2336. Pads zero.
#define W1_OFF 0
#define W2_OFF 288
#define W3_OFF 1248
#define B1_OFF 2208
#define B2_OFF 2240
#define B3_OFF 2272
#define W4_OFF 2304
#define B4_OFF 2336

// R6-R12 established: SMEM weight delivery = ~105 serial uncounted-wait
// round-trips (lgkmcnt(0) full drain; SMEM completes out-of-order so no
// counted waits) -> ~85% stall. LDS ds_read has counted in-order lgkmcnt ->
// pipelines. R3/R4's LDS blowup was the UNCAPPED allocator (256 VGPR);
// cap at 85 (natural live set ~84) + per-row fences keeps it tight.
// Same-address broadcast ds_reads are bank-conflict free.
__global__ __launch_bounds__(256, 3) void mlp_fwdbwd(
    const float4* __restrict__ pe,
    const float*  __restrict__ q,
    const float4* __restrict__ s,
    const float* __restrict__ W1, const float* __restrict__ b1,
    const float* __restrict__ W2, const float* __restrict__ b2,
    const float* __restrict__ W3, const float* __restrict__ b3,
    const float* __restrict__ W4, const float* __restrict__ b4,
    float* __restrict__ dout, int n)
{
    __shared__ float lw[2368];
    const int tid = threadIdx.x;
    for (int idx = tid; idx < 2368; idx += 256) {
        float v = 0.f;
        if (idx < 288)        { int t = idx,        r = t >> 5, c = t & 31; v = (c < DH) ? W1[r * DH + c] : 0.f; }
        else if (idx < 1248)  { int t = idx - 288,  r = t >> 5, c = t & 31; v = (c < DH) ? W2[r * DH + c] : 0.f; }
        else if (idx < 2208)  { int t = idx - 1248, r = t >> 5, c = t & 31; v = (c < DH) ? W3[r * DH + c] : 0.f; }
        else if (idx < 2240)  { int c = idx - 2208; v = (c < DH) ? b1[c] : 0.f; }
        else if (idx < 2272)  { int c = idx - 2240; v = (c < DH) ? b2[c] : 0.f; }
        else if (idx < 2304)  { int c = idx - 2272; v = (c < DH) ? b3[c] : 0.f; }
        else if (idx < 2336)  { int c = idx - 2304; v = (c < DH) ? W4[c] : 0.f; }
        else if (idx == 2336) { v = b4[0]; }
        lw[idx] = v;
    }
    __syncthreads();

    const int i = blockIdx.x * 256 + tid;
    if (i >= n) return;

    const float4 vpe = pe[i];
    const float4 vs  = s[i];
    const float  vq  = q[i];
    float x[9] = { vpe.x, vpe.y, vpe.z, vpe.w, vq, vs.x, vs.y, vs.z, vs.w };

    v2 acc[15];
    v2 hh[15];
    unsigned m1 = 0, m2 = 0, m3 = 0;
    const v2 slope2 = { SLOPE, SLOPE };

    // ---- layer 1: (x @ W1) then + b1 (acc from 0, k ascending, fma) ----
    #pragma unroll
    for (int jj = 0; jj < 15; ++jj) acc[jj] = (v2){0.f, 0.f};
    #pragma unroll
    for (int k = 0; k < 9; ++k) {
        const v2 xv = { x[k], x[k] };
        const v2* Wr = reinterpret_cast<const v2*>(lw + W1_OFF + k * 32);
        #pragma unroll
        for (int jj = 0; jj < 15; ++jj)
            acc[jj] = __builtin_elementwise_fma(xv, Wr[jj], acc[jj]);
        SB();
    }
    {
        const v2* bv = reinterpret_cast<const v2*>(lw + B1_OFF);
        #pragma unroll
        for (int jj = 0; jj < 15; ++jj) {
            const v2 z = acc[jj] + bv[jj];
            if (z.x > 0.f) m1 |= (1u << (2*jj));
            if (z.y > 0.f) m1 |= (1u << (2*jj+1));
            // bit-identical to (z>0?z:0.01*z)
            hh[jj] = __builtin_elementwise_max(z, z * slope2);
        }
    }
    SB();

    // ---- layer 2 ----
    #pragma unroll
    for (int jj = 0; jj < 15; ++jj) acc[jj] = (v2){0.f, 0.f};
    #pragma unroll
    for (int k = 0; k < DH; ++k) {
        const float hk = hh[k >> 1][k & 1];
        const v2 hv = { hk, hk };
        const v2* Wr = reinterpret_cast<const v2*>(lw + W2_OFF + k * 32);
        #pragma unroll
        for (int jj = 0; jj < 15; ++jj)
            acc[jj] = __builtin_elementwise_fma(hv, Wr[jj], acc[jj]);
        SB();
    }
    {
        const v2* bv = reinterpret_cast<const v2*>(lw + B2_OFF);
        #pragma unroll
        for (int jj = 0; jj < 15; ++jj) {
            const v2 z = acc[jj] + bv[jj];
            if (z.x > 0.f) m2 |= (1u << (2*jj));
            if (z.y > 0.f) m2 |= (1u << (2*jj+1));
            hh[jj] = __builtin_elementwise_max(z, z * slope2);
        }
    }
    SB();

    // ---- layer 3 ----
    #pragma unroll
    for (int jj = 0; jj < 15; ++jj) acc[jj] = (v2){0.f, 0.f};
    #pragma unroll
    for (int k = 0; k < DH; ++k) {
        const float hk = hh[k >> 1][k & 1];
        const v2 hv = { hk, hk };
        const v2* Wr = reinterpret_cast<const v2*>(lw + W3_OFF + k * 32);
        #pragma unroll
        for (int jj = 0; jj < 15; ++jj)
            acc[jj] = __builtin_elementwise_fma(hv, Wr[jj], acc[jj]);
        SB();
    }
    // output dot: scalar, j ascending (bit-identical to passing R6/R8 kernels)
    const float* b3p = lw + B3_OFF;
    const float* W4p = lw + W4_OFF;
    float outv = 0.f;
    #pragma unroll
    for (int j = 0; j < DH; ++j) {
        const float z = acc[j >> 1][j & 1] + b3p[j];
        if (z > 0.f) m3 |= (1u << j);
        const float hz = (z > 0.f) ? z : SLOPE * z;
        outv = fmaf(hz, W4p[j], outv);
    }
    outv += lw[B4_OFF];
    SB();

    // ---- backward (mask-driven; value-continuous, packed dots) ----
    v2 g3[15];
    {
        const v2* w4v = reinterpret_cast<const v2*>(W4p);
        #pragma unroll
        for (int jj = 0; jj < 15; ++jj) {
            const v2 w = w4v[jj];
            g3[jj].x = ((m3 >> (2*jj))   & 1u) ? w.x : SLOPE * w.x;
            g3[jj].y = ((m3 >> (2*jj+1)) & 1u) ? w.y : SLOPE * w.y;
        }
    }
    v2 g2[15];
    #pragma unroll
    for (int k = 0; k < DH; ++k) {
        v2 d = (v2){0.f, 0.f};
        const v2* Wr = reinterpret_cast<const v2*>(lw + W3_OFF + k * 32);
        #pragma unroll
        for (int jj = 0; jj < 15; ++jj)
            d = __builtin_elementwise_fma(g3[jj], Wr[jj], d);
        const float dot = d.x + d.y;
        g2[k >> 1][k & 1] = ((m2 >> k) & 1u) ? dot : SLOPE * dot;
        SB();
    }
    v2 g1[15];
    #pragma unroll
    for (int k = 0; k < DH; ++k) {
        v2 d = (v2){0.f, 0.f};
        const v2* Wr = reinterpret_cast<const v2*>(lw + W2_OFF + k * 32);
        #pragma unroll
        for (int jj = 0; jj < 15; ++jj)
            d = __builtin_elementwise_fma(g2[jj], Wr[jj], d);
        const float dot = d.x + d.y;
        g1[k >> 1][k & 1] = ((m1 >> k) & 1u) ? dot : SLOPE * dot;
        SB();
    }
    float gx[9];
    #pragma unroll
    for (int k = 0; k < 9; ++k) {
        v2 d = (v2){0.f, 0.f};
        const v2* Wr = reinterpret_cast<const v2*>(lw + W1_OFF + k * 32);
        #pragma unroll
        for (int jj = 0; jj < 15; ++jj)
            d = __builtin_elementwise_fma(g1[jj], Wr[jj], d);
        gx[k] = d.x + d.y;
        SB();
    }

    // ---- stores: [out(N) | h_s(4N) | h_q(N) | h_pe(4N)] ----
    dout[i] = outv;
    float4* hs = reinterpret_cast<float4*>(dout + (size_t)n);
    hs[i] = make_float4(gx[5], gx[6], gx[7], gx[8]);
    dout[(size_t)5 * n + i] = gx[4];
    float4* hpe = reinterpret_cast<float4*>(dout + (size_t)6 * n);
    hpe[i] = make_float4(gx[0], gx[1], gx[2], gx[3]);
}

extern "C" void kernel_launch(void* const* d_in, const int* in_sizes, int n_in,
                              void* d_out, int out_size, void* d_ws, size_t ws_size,
                              hipStream_t stream) {
    const int n = in_sizes[1];  // input_q has N elements
    const int blocks = (n + 255) / 256;
    hipLaunchKernelGGL(mlp_fwdbwd, dim3(blocks), dim3(256), 0, stream,
        (const float4*)d_in[0], (const float*)d_in[1], (const float4*)d_in[2],
        (const float*)d_in[3], (const float*)d_in[4],
        (const float*)d_in[5], (const float*)d_in[6],
        (const float*)d_in[7], (const float*)d_in[8],
        (const float*)d_in[9], (const float*)d_in[10],
        (float*)d_out, n);
}